// Round 3
// baseline (3081.895 us; speedup 1.0000x reference)
//
#include <hip/hip_runtime.h>

#define N_EMBD 512
#define HID 66
#define T_STEPS 8
#define BLK 64

__device__ __forceinline__ float fast_rcp(float a) {
    float r = __builtin_amdgcn_rcpf(a);
    r = r * (2.0f - a * r);   // one Newton step -> ~1e-7 rel
    return r;
}
__device__ __forceinline__ float fast_exp(float x) {
    x = fminf(x, 60.0f);      // clamp to avoid inf -> NaN in Newton rcp
    return __expf(x);
}
__device__ __forceinline__ float sigmoid_f(float x) {
    return fast_rcp(1.0f + fast_exp(-x));
}
__device__ __forceinline__ float tanh_f(float x) {
    // 1 - 2/(e^{2x}+1): exact at saturation, no inf/NaN
    return 1.0f - 2.0f * fast_rcp(1.0f + fast_exp(2.0f * x));
}

// One batch element per thread. NO LDS anywhere: h[] and hn[] live in VGPRs
// (all indices compile-time via full unroll). Weight addresses are all
// base + literal offset (j unrolled) -> wave-uniform s_load streams the
// compiler can prefetch arbitrarily deep. Only 2048 waves exist (B/64), so
// 2 waves/SIMD is the occupancy ceiling -> launch_bounds(64,2) gives the
// allocator the full 256-VGPR budget (no spills for ~165 live floats).
__global__ __launch_bounds__(BLK, 2) void wp_grurefine_kernel(
    const float* __restrict__ x_last,      // [B,8,2]
    const float* __restrict__ cls_emb,     // [B,512]
    const float* __restrict__ tp,          // [B,2]
    const float* __restrict__ light,       // [B,1]
    const float* __restrict__ cmd,         // [B,1]
    const float* __restrict__ bbox,        // [B,1,8,10]
    const float* __restrict__ W_head,      // [64,512]
    const float* __restrict__ b_head,      // [64]
    const float* __restrict__ W_ih,        // [198,16]
    const float* __restrict__ W_hh,        // [198,66]
    const float* __restrict__ b_ih,        // [198]
    const float* __restrict__ b_hh,        // [198]
    const float* __restrict__ W_out,       // [2,66]
    const float* __restrict__ b_out,       // [2]
    float* __restrict__ out,               // [B,8,2]
    int Btotal)
{
    const int b = blockIdx.x * BLK + threadIdx.x;
    if (b >= Btotal) return;

    // ---------------- head: h[0:64] = cls_emb[b] @ W_head.T + b_head ----------------
    float h[HID];
    #pragma unroll
    for (int j = 0; j < 64; ++j) h[j] = b_head[j];

    const float* cls = cls_emb + (size_t)b * N_EMBD;
    #pragma unroll 1
    for (int k0 = 0; k0 < N_EMBD; k0 += 8) {
        const float4 c0 = *(const float4*)(cls + k0);
        const float4 c1 = *(const float4*)(cls + k0 + 4);
        #pragma unroll
        for (int j = 0; j < 64; ++j) {
            const float* wr = W_head + j * N_EMBD + k0;   // uniform -> s_load
            float acc = h[j];
            acc = fmaf(c0.x, wr[0], acc);
            acc = fmaf(c0.y, wr[1], acc);
            acc = fmaf(c0.z, wr[2], acc);
            acc = fmaf(c0.w, wr[3], acc);
            acc = fmaf(c1.x, wr[4], acc);
            acc = fmaf(c1.y, wr[5], acc);
            acc = fmaf(c1.z, wr[6], acc);
            acc = fmaf(c1.w, wr[7], acc);
            h[j] = acc;
        }
    }
    h[64] = light[b];
    h[65] = cmd[b];

    // ---------------- GRU over 8 steps (fully unrolled j, registers only) ----------------
    const float2 tpv = *(const float2*)(tp + (size_t)b * 2);
    const float tp0 = tpv.x, tp1 = tpv.y;
    const float* xlr  = x_last + (size_t)b * (T_STEPS * 2);
    const float* bbr  = bbox   + (size_t)b * (T_STEPS * 10);
    float*       outr = out    + (size_t)b * (T_STEPS * 2);

    float x0 = 0.0f, x1 = 0.0f;

    #pragma unroll 1
    for (int t = 0; t < T_STEPS; ++t) {
        float xin[16];
        xin[0] = x0;  xin[1] = x1;
        xin[2] = tp0; xin[3] = tp1;
        {
            const float2 xl2 = *(const float2*)(xlr + t * 2);
            xin[4] = xl2.x; xin[5] = xl2.y;
        }
        #pragma unroll
        for (int q = 0; q < 5; ++q) {
            const float2 bq = *(const float2*)(bbr + t * 10 + q * 2);  // 8B-aligned
            xin[6 + 2 * q] = bq.x;
            xin[7 + 2 * q] = bq.y;
        }

        float hn[HID];
        #pragma unroll
        for (int j = 0; j < HID; ++j) {          // FULLY unrolled: j is constant
            const float* wir = W_ih + j * 16;
            const float* wiu = W_ih + (HID + j) * 16;
            const float* win = W_ih + (2 * HID + j) * 16;
            const float* whr = W_hh + j * HID;
            const float* whu = W_hh + (HID + j) * HID;
            const float* whn = W_hh + (2 * HID + j) * HID;

            float gr  = b_ih[j]           + b_hh[j];
            float gu  = b_ih[HID + j]     + b_hh[HID + j];
            float gin = b_ih[2 * HID + j];
            float ghn = b_hh[2 * HID + j];

            #pragma unroll
            for (int k = 0; k < 16; ++k) {
                gr  = fmaf(xin[k], wir[k], gr);
                gu  = fmaf(xin[k], wiu[k], gu);
                gin = fmaf(xin[k], win[k], gin);
            }
            #pragma unroll
            for (int k = 0; k < HID; ++k) {
                gr  = fmaf(h[k], whr[k], gr);
                gu  = fmaf(h[k], whu[k], gu);
                ghn = fmaf(h[k], whn[k], ghn);
            }

            const float r = sigmoid_f(gr);
            const float u = sigmoid_f(gu);
            const float n = tanh_f(fmaf(r, ghn, gin));
            hn[j] = (1.0f - u) * n + u * h[j];   // constant-index register access
        }

        // commit h_new and fuse the waypoint head
        float a0 = b_out[0], a1 = b_out[1];
        #pragma unroll
        for (int j = 0; j < HID; ++j) {
            const float z = hn[j];
            h[j] = z;
            a0 = fmaf(z, W_out[j],       a0);
            a1 = fmaf(z, W_out[HID + j], a1);
        }
        x0 += a0;
        x1 += a1;

        outr[t * 2 + 0] = x0 - 1.3f;
        outr[t * 2 + 1] = x1;
    }
}

extern "C" void kernel_launch(void* const* d_in, const int* in_sizes, int n_in,
                              void* d_out, int out_size, void* d_ws, size_t ws_size,
                              hipStream_t stream) {
    const float* x_last  = (const float*)d_in[0];
    const float* cls_emb = (const float*)d_in[1];
    const float* tp      = (const float*)d_in[2];
    const float* light   = (const float*)d_in[3];
    const float* cmd     = (const float*)d_in[4];
    const float* bbox    = (const float*)d_in[5];
    const float* W_head  = (const float*)d_in[6];
    const float* b_head  = (const float*)d_in[7];
    const float* W_ih    = (const float*)d_in[8];
    const float* W_hh    = (const float*)d_in[9];
    const float* b_ih    = (const float*)d_in[10];
    const float* b_hh    = (const float*)d_in[11];
    const float* W_out   = (const float*)d_in[12];
    const float* b_out   = (const float*)d_in[13];
    float* out = (float*)d_out;

    const int Btotal = in_sizes[1] / N_EMBD;
    dim3 grid((Btotal + BLK - 1) / BLK);
    wp_grurefine_kernel<<<grid, BLK, 0, stream>>>(
        x_last, cls_emb, tp, light, cmd, bbox,
        W_head, b_head, W_ih, W_hh, b_ih, b_hh, W_out, b_out,
        out, Btotal);
}